// Round 3
// baseline (439.563 us; speedup 1.0000x reference)
//
#include <hip/hip_runtime.h>

#define BIG_Z_F 1000000.0f
#define N_MESH 8

// Native Clang vector type for 16B face-row loads.
typedef float f4 __attribute__((ext_vector_type(4)));

// R12: NT-store A/B. Counter forensics: dur_us ~= one fixed ~205us harness
// fill (plain stores, 6.4 TB/s, 1.31 GB) + our kernels (~182-200us, never in
// top-5 so <202us each). Our byte floor is ~65us -> kernel runs at ~2 TB/s
// effective. Stores are 85% of our bytes and ALL non-temporal; the fill
// proves the PLAIN store path hits 80% of peak. Gather thrash is rebutted by
// the data distribution (~7/8 of lanes gather face 0 = broadcast).
// Single change vs R11: every __builtin_nontemporal_store -> plain store.
// Loads unchanged (NT on p2f/dists, cached on zbuf/bary/fmem).
// Plus: test-before-set guard on vv scatter (benign race; cuts same-line
// write storms to the 40KB vv region).

// ---------------------------------------------------------------------------
// Tiny init kernel: zero vertex-visibility accumulator (40 KB).
// ---------------------------------------------------------------------------
__global__ __launch_bounds__(256) void zero_vv(
    float* __restrict__ vv, int V)
{
    const int i = blockIdx.x * blockDim.x + threadIdx.x;
    if (i < V) vv[i] = 0.0f;
}

// ---------------------------------------------------------------------------
// Fused kernel: per-(mesh, pixel). Cross-mesh reduction + mask/zb +
// p/d/bc outputs + gather-interp out_map + direct vv scatter.
// ---------------------------------------------------------------------------
__global__ __launch_bounds__(256) void raster_fused(
    const float* __restrict__ zbuf,   // (N, HW) — cached loads, 8x reuse
    const int*   __restrict__ p2f,    // (N, HW)
    const float* __restrict__ bary,   // (N, HW, 3)
    const float* __restrict__ dists,  // (N, HW)
    const float* __restrict__ fmem,   // (F,3,C) — row = 32 fl = one 128B line
    const int*   __restrict__ pfaces, // (F,3)
    const int*   __restrict__ mdp,    // scalar mask_duplicate
    float* __restrict__ out_map,      // (N,C,HW)
    float* __restrict__ maskO,        // (N, HW)
    float* __restrict__ zbO,          // (N, HW)
    float* __restrict__ pO,           // (N, HW)
    float* __restrict__ dO,           // (N, HW)
    float* __restrict__ bcO,          // (N, HW, 3)
    float* __restrict__ vv,           // (V), pre-zeroed by zero_vv
    int HW, int C)
{
    const int pix = blockIdx.x * blockDim.x + threadIdx.x;
    if (pix >= HW) return;
    const int n   = blockIdx.y;
    const int idx = n * HW + pix;
    const int md  = *mdp;

    // ---- cross-mesh reduction (running scalars; no runtime-indexed array)
    int   cnt  = 0;
    float best = __builtin_inff();
    int   bi   = 0;
    float zown = 0.0f;
    #pragma unroll
    for (int nn = 0; nn < N_MESH; ++nn) {
        const float zv = zbuf[nn * HW + pix];   // plain load: L2/L3-resident
        if (nn == n) zown = zv;                 // uniform select (n uniform)
        cnt += (zv > -1.0f) ? 1 : 0;
        const float t = (zv < 0.0f) ? BIG_Z_F : zv;
        if (t < best) { best = t; bi = nn; }    // strict < => first-win tie
    }
    const bool dup = (cnt > 1) && ((md != 0) || (n != bi));

    maskO[idx] = (zown >= 0.0f) ? 1.0f : 0.0f;
    zbO[idx]   = dup ? -1.0f : zown;

    // ---- per-pixel p/d/bc outputs (same semantics as R9/R10/R11)
    const int   praw = __builtin_nontemporal_load(&p2f[idx]);
    const float drw  = __builtin_nontemporal_load(&dists[idx]);
    const float br0  = bary[idx * 3 + 0];   // plain: stride-12, L1-shared
    const float br1  = bary[idx * 3 + 1];
    const float br2  = bary[idx * 3 + 2];

    const int  p     = dup ? -1 : praw;
    const bool valid = (p >= 0);
    const int  safe  = valid ? p : 0;

    const float bst0 = dup ? -1.0f : br0;
    const float bst1 = dup ? -1.0f : br1;
    const float bst2 = dup ? -1.0f : br2;
    const float bc0  = valid ? bst0 : 0.0f;
    const float bc1  = valid ? bst1 : 0.0f;
    const float bc2  = valid ? bst2 : 0.0f;

    pO[idx] = (float)p;
    dO[idx] = dup ? -1.0f : drw;
    bcO[idx * 3 + 0] = bst0;
    bcO[idx * 3 + 1] = bst1;
    bcO[idx * 3 + 2] = bst2;

    // ---- direct vertex-visibility scatter (~1/8 lanes active).
    // Test-before-set: reads are L1/L2-shareable; stores only for cold flags
    // (benign race — value only ever transitions to 1.0f).
    if (valid) {
        const int b = safe * 3;
        const int v0 = pfaces[b + 0];
        const int v1 = pfaces[b + 1];
        const int v2 = pfaces[b + 2];
        if (vv[v0] != 1.0f) vv[v0] = 1.0f;
        if (vv[v1] != 1.0f) vv[v1] = 1.0f;
        if (vv[v2] != 1.0f) vv[v2] = 1.0f;
    }

    // ---- gather + interp: row-outer / channel-inner, per-pixel accumulator.
    // ~7/8 of lanes have safe==0 (broadcast line, free); ~1/8 gather a random
    // face. acc association matches bc0*a0 + bc1*a1 + bc2*a2.
    const float* a = fmem + (size_t)safe * 3 * C;
    f4 acc[8];
    #pragma unroll
    for (int c4 = 0; c4 < 8; ++c4) {
        const f4 a0 = *(const f4*)(a + 4 * c4);
        acc[c4] = bc0 * a0;
    }
    #pragma unroll
    for (int c4 = 0; c4 < 8; ++c4) {
        const f4 a1 = *(const f4*)(a + C + 4 * c4);
        acc[c4] += bc1 * a1;
    }
    #pragma unroll
    for (int c4 = 0; c4 < 8; ++c4) {
        const f4 a2 = *(const f4*)(a + 2 * C + 4 * c4);
        acc[c4] += bc2 * a2;
    }

    // Stores: channel-major out (n,C,HW); lanes cover consecutive pix ->
    // each 4B plain store instruction is a full coalesced 256B segment.
    #pragma unroll
    for (int c4 = 0; c4 < 8; ++c4) {
        #pragma unroll
        for (int k = 0; k < 4; ++k) {
            out_map[(size_t)(n * C + c4 * 4 + k) * HW + pix] = acc[c4][k];
        }
    }
}

extern "C" void kernel_launch(void* const* d_in, const int* in_sizes, int n_in,
                              void* d_out, int out_size, void* d_ws, size_t ws_size,
                              hipStream_t stream) {
    const float* zbuf   = (const float*)d_in[0];
    const int*   p2f    = (const int*)  d_in[1];
    const float* bary   = (const float*)d_in[2];
    const float* dists  = (const float*)d_in[3];
    const float* fmem   = (const float*)d_in[4];
    const int*   pfaces = (const int*)  d_in[5];
    // d_in[6] = num_verts (device scalar; V derived from out_size instead)
    const int*   mdp    = (const int*)  d_in[7];

    const long long P  = in_sizes[0];        // N*H*W*K = 2097152
    const int HW  = (int)(P / N_MESH);       // 262144 pixels
    const int F3  = in_sizes[5];             // F*3
    const int C   = in_sizes[4] / F3;        // 32
    const int V   = (int)((long long)out_size - P * C - 7 * P);  // 10002

    float* out     = (float*)d_out;
    float* out_map = out;                    // P*C
    float* vv      = out_map + P * C;        // V
    float* maskO   = vv + V;                 // P
    float* zbO     = maskO + P;              // P
    float* pO      = zbO + P;                // P
    float* dO      = pO + P;                 // P
    float* bcO     = dO + P;                 // 3P

    zero_vv<<<dim3((V + 255) / 256), dim3(256), 0, stream>>>(vv, V);

    raster_fused<<<dim3(HW / 256, N_MESH), dim3(256), 0, stream>>>(
        zbuf, p2f, bary, dists, fmem, pfaces, mdp,
        out_map, maskO, zbO, pO, dO, bcO,
        vv, HW, C);
}

// Round 4
// 410.975 us; speedup vs baseline: 1.0696x; 1.0696x over previous
//
#include <hip/hip_runtime.h>

#define BIG_Z_F 1000000.0f
#define N_MESH 8

// Native Clang vector types — required by __builtin_nontemporal_* (HIP's
// float4/int4 are structs and are rejected by the builtin).
typedef float f4 __attribute__((ext_vector_type(4)));
typedef int   i4 __attribute__((ext_vector_type(4)));
typedef unsigned char uc4 __attribute__((ext_vector_type(4)));

// R13 = exact R9 structure (best measured: 386.9us) with ONE change:
// kernel B's output stores (out_map/pO/dO/bcO) are PLAIN 16B stores, not NT.
// Rationale: R9's kernel side runs ~182us vs a ~60us byte floor while the
// harness fill proves plain stores sustain 6.4 TB/s. In the R9 structure
// kernel B has no L2 reuse for plain stores to pollute (zbuf only read in A;
// bary/p2f/dists are single-use NT loads), so if NT stores bypass L2 write-
// combining (16B bursts to HBM = ~2x write amplification), plain fixes it.
// R12's plain-store regression was measured on the WRONG structure (scalar
// 4B stores, fused kernel relying on zbuf L2 reuse) — not a valid A/B.
// Lessons kept: R10/R11/R12 fusion+scalarization all regressed; do not
// re-fuse, do not scalarize, do not re-batch (R8).

// ---------------------------------------------------------------------------
// Kernel A: per-4-pixel cross-mesh reduction + ws zero-init.
// win[j] = dup0 ? argmin : 0xFF.  (unchanged from R9, NT throughout)
// ---------------------------------------------------------------------------
__global__ __launch_bounds__(256) void raster_reduce(
    const f4* __restrict__ zbuf4,   // (N, HW/4)
    f4* __restrict__ maskO4,        // (N, HW/4)
    f4* __restrict__ zbO4,          // (N, HW/4)
    uc4* __restrict__ win4,         // (HW/4) ws
    int* __restrict__ faceflag,     // (F+1) ws — zeroed here, used by B
    float* __restrict__ vv,         // (V) out — zeroed here, used by vert_vis
    const int* __restrict__ mdp,    // scalar mask_duplicate
    int HW4, int F, int V)
{
    const int q = blockIdx.x * blockDim.x + threadIdx.x;
    if (q >= HW4) return;

    // Folded zero-init (A runs before B / vert_vis; stream-ordered).
    if (q <= F) faceflag[q] = 0;
    if (q < V)  vv[q] = 0.0f;

    const int md = *mdp;

    float z[N_MESH][4];
    #pragma unroll
    for (int n = 0; n < N_MESH; ++n) {
        const f4 v = __builtin_nontemporal_load(&zbuf4[n * HW4 + q]);
        z[n][0] = v.x; z[n][1] = v.y; z[n][2] = v.z; z[n][3] = v.w;
    }

    bool dup0[4]; int bidx[4];
    #pragma unroll
    for (int j = 0; j < 4; ++j) {
        int count = 0; float best = __builtin_inff(); int bi = 0;
        #pragma unroll
        for (int n = 0; n < N_MESH; ++n) {
            const float zv = z[n][j];
            count += (zv > -1.0f) ? 1 : 0;
            const float t = (zv < 0.0f) ? BIG_Z_F : zv;
            if (t < best) { best = t; bi = n; }   // strict < => first-win tie
        }
        dup0[j] = (count > 1);
        bidx[j] = bi;
    }

    #pragma unroll
    for (int n = 0; n < N_MESH; ++n) {
        f4 m, zb;
        #pragma unroll
        for (int j = 0; j < 4; ++j) {
            const bool dup = dup0[j] && ((md != 0) || (n != bidx[j]));
            m[j]  = (z[n][j] >= 0.0f) ? 1.0f : 0.0f;
            zb[j] = dup ? -1.0f : z[n][j];
        }
        __builtin_nontemporal_store(m,  &maskO4[n * HW4 + q]);
        __builtin_nontemporal_store(zb, &zbO4[n * HW4 + q]);
    }
    uc4 w;
    w.x = dup0[0] ? (unsigned char)bidx[0] : (unsigned char)0xFF;
    w.y = dup0[1] ? (unsigned char)bidx[1] : (unsigned char)0xFF;
    w.z = dup0[2] ? (unsigned char)bidx[2] : (unsigned char)0xFF;
    w.w = dup0[3] ? (unsigned char)bidx[3] : (unsigned char)0xFF;
    win4[q] = w;
}

// ---------------------------------------------------------------------------
// Kernel B: per-(mesh, 4 pixels). Fully branchless gather/interp path.
// R13 change: output stores are PLAIN (16B) — the NT-vs-plain store A/B.
// ---------------------------------------------------------------------------
__global__ __launch_bounds__(256) void raster_interp(
    const i4* __restrict__ p2f4,    // (N, HW/4)
    const f4* __restrict__ bary4,   // (N, HW/4, 3)
    const f4* __restrict__ dists4,  // (N, HW/4)
    const float* __restrict__ fmem, // (F,3,C)
    const uc4* __restrict__ win4,   // (HW/4)
    const int* __restrict__ mdp,
    f4* __restrict__ out_map4,      // (N,C,HW/4)
    f4* __restrict__ pO4,           // (N, HW/4)
    f4* __restrict__ dO4,           // (N, HW/4)
    f4* __restrict__ bcO4,          // (N, HW/4, 3)
    int* __restrict__ faceflag,     // (F+1) ws, pre-zeroed; slot F = dummy
    int HW4, int C, int F)
{
    const int q = blockIdx.x * blockDim.x + threadIdx.x;
    if (q >= HW4) return;
    const int n    = blockIdx.y;
    const int idx4 = n * HW4 + q;
    const int md   = *mdp;

    const uc4 wv = win4[q];
    const unsigned char w[4] = { wv.x, wv.y, wv.z, wv.w };

    const i4 praw = __builtin_nontemporal_load(&p2f4[idx4]);
    const f4 drw  = __builtin_nontemporal_load(&dists4[idx4]);
    const f4 bv0  = __builtin_nontemporal_load(&bary4[idx4 * 3 + 0]); // p0.xyz p1.x
    const f4 bv1  = __builtin_nontemporal_load(&bary4[idx4 * 3 + 1]); // p1.yz  p2.xy
    const f4 bv2  = __builtin_nontemporal_load(&bary4[idx4 * 3 + 2]); // p2.z   p3.xyz
    const int   pr[4] = { praw.x, praw.y, praw.z, praw.w };
    const float dr[4] = { drw.x, drw.y, drw.z, drw.w };
    const float br[4][3] = {
        { bv0.x, bv0.y, bv0.z },
        { bv0.w, bv1.x, bv1.y },
        { bv1.z, bv1.w, bv2.x },
        { bv2.y, bv2.z, bv2.w },
    };

    float bst[4][3];   // values stored to bcO (dup -> -1)
    float bc[4][3];    // compute coefficients (invalid -> 0 => out = 0)
    int   safe[4];
    f4 pOv, dOv;
    #pragma unroll
    for (int j = 0; j < 4; ++j) {
        const bool dup   = (w[j] != 0xFF) && ((md != 0) || (n != (int)w[j]));
        const int  p     = dup ? -1 : pr[j];
        const bool valid = (p >= 0);
        #pragma unroll
        for (int k = 0; k < 3; ++k) {
            bst[j][k] = dup ? -1.0f : br[j][k];
            bc[j][k]  = valid ? bst[j][k] : 0.0f;
        }
        safe[j] = valid ? p : 0;
        pOv[j]  = (float)p;
        dOv[j]  = dup ? -1.0f : dr[j];
        faceflag[valid ? p : F] = 1;   // branchless scatter; slot F = dummy
    }
    pO4[idx4] = pOv;                   // PLAIN stores (R13 A/B)
    dO4[idx4] = dOv;
    {
        f4 c0, c1, c2;
        c0.x = bst[0][0]; c0.y = bst[0][1]; c0.z = bst[0][2]; c0.w = bst[1][0];
        c1.x = bst[1][1]; c1.y = bst[1][2]; c1.z = bst[2][0]; c1.w = bst[2][1];
        c2.x = bst[2][2]; c2.y = bst[3][0]; c2.z = bst[3][1]; c2.w = bst[3][2];
        bcO4[idx4 * 3 + 0] = c0;
        bcO4[idx4 * 3 + 1] = c1;
        bcO4[idx4 * 3 + 2] = c2;
    }

    const float* ab[4];
    #pragma unroll
    for (int j = 0; j < 4; ++j)
        ab[j] = fmem + (size_t)safe[j] * 3 * C;

    #pragma unroll
    for (int c4 = 0; c4 < 32; c4 += 4) {     // C == 32
        f4 r[4];   // r[j] = channels c4..c4+3 of pixel j (channel-major)
        #pragma unroll
        for (int j = 0; j < 4; ++j) {
            const float* a = ab[j];
            const f4 a0 = *(const f4*)(a + c4);
            const f4 a1 = *(const f4*)(a + C + c4);
            const f4 a2 = *(const f4*)(a + 2 * C + c4);
            r[j] = bc[j][0] * a0 + bc[j][1] * a1 + bc[j][2] * a2;
        }
        #pragma unroll
        for (int k = 0; k < 4; ++k) {        // transpose to pixel-major
            f4 o;
            o.x = r[0][k]; o.y = r[1][k]; o.z = r[2][k]; o.w = r[3][k];
            out_map4[(size_t)(n * C + c4 + k) * HW4 + q] = o;   // PLAIN (R13)
        }
    }
}

// Scatter vertex visibility from face-visibility flags. (unchanged from R9)
__global__ __launch_bounds__(256) void vert_vis(
    const int* __restrict__ faceflag,
    const int* __restrict__ pfaces,     // (F,3)
    float* __restrict__ vv,             // (V), pre-zeroed by kernel A
    int F)
{
    const int f = blockIdx.x * blockDim.x + threadIdx.x;
    if (f >= F) return;
    if (faceflag[f]) {
        vv[pfaces[f * 3 + 0]] = 1.0f;
        vv[pfaces[f * 3 + 1]] = 1.0f;
        vv[pfaces[f * 3 + 2]] = 1.0f;
    }
}

extern "C" void kernel_launch(void* const* d_in, const int* in_sizes, int n_in,
                              void* d_out, int out_size, void* d_ws, size_t ws_size,
                              hipStream_t stream) {
    const float* zbuf   = (const float*)d_in[0];
    const int*   p2f    = (const int*)  d_in[1];
    const float* bary   = (const float*)d_in[2];
    const float* dists  = (const float*)d_in[3];
    const float* fmem   = (const float*)d_in[4];
    const int*   pfaces = (const int*)  d_in[5];
    // d_in[6] = num_verts (device scalar; V derived from out_size instead)
    const int*   mdp    = (const int*)  d_in[7];

    const long long P  = in_sizes[0];        // N*H*W*K = 2097152
    const int HW  = (int)(P / N_MESH);       // 262144 pixels
    const int HW4 = HW / 4;                  // 65536
    const int F3  = in_sizes[5];             // F*3
    const int F   = F3 / 3;                  // 20000
    const int C   = in_sizes[4] / F3;        // 32
    const int V   = (int)((long long)out_size - P * C - 7 * P);  // 10002

    float* out     = (float*)d_out;
    float* out_map = out;                    // P*C
    float* vv      = out_map + P * C;        // V
    float* maskO   = vv + V;                 // P
    float* zbO     = maskO + P;              // P
    float* pO      = zbO + P;                // P
    float* dO      = pO + P;                 // P
    float* bcO     = dO + P;                 // 3P

    int* faceflag = (int*)d_ws;                 // F+1 ints (slot F = dummy)
    uc4* win4     = (uc4*)(faceflag + F + 4);   // HW bytes

    raster_reduce<<<dim3(HW4 / 256), dim3(256), 0, stream>>>(
        (const f4*)zbuf, (f4*)maskO, (f4*)zbO, win4, faceflag, vv, mdp,
        HW4, F, V);

    raster_interp<<<dim3(HW4 / 256, N_MESH), dim3(256), 0, stream>>>(
        (const i4*)p2f, (const f4*)bary, (const f4*)dists, fmem,
        (const uc4*)win4, mdp,
        (f4*)out_map, (f4*)pO, (f4*)dO, (f4*)bcO,
        faceflag, HW4, C, F);

    vert_vis<<<dim3((F + 255) / 256), dim3(256), 0, stream>>>(
        faceflag, pfaces, vv, F);
}